// Round 1
// baseline (309.978 us; speedup 1.0000x reference)
//
#include <hip/hip_runtime.h>

#define H 32
#define Q 64
#define S 8192
#define D 128
#define OBS 16
#define L 2048

// Kernel 1: priority[h][s] = mean over last OBS queries of attn[0,h,q,s]
__global__ void k_priority(const float* __restrict__ attn, float* __restrict__ prio) {
    int gid = blockIdx.x;              // 0..255
    int h = gid >> 3;                  // 32 heads
    int chunk = gid & 7;               // 8 chunks of 1024 floats
    int s4 = chunk * 1024 + threadIdx.x * 4;
    const float4* base = (const float4*)(attn + ((size_t)(h * Q + (Q - OBS)) * S + s4));
    float4 acc = make_float4(0.f, 0.f, 0.f, 0.f);
#pragma unroll
    for (int qq = 0; qq < OBS; ++qq) {
        float4 v = base[qq * (S / 4)];
        acc.x += v.x; acc.y += v.y; acc.z += v.z; acc.w += v.w;
    }
    const float inv = 1.0f / (float)OBS;
    acc.x *= inv; acc.y *= inv; acc.z *= inv; acc.w *= inv;
    *((float4*)(prio + (size_t)h * S + s4)) = acc;
}

// Kernel 2: per-head avg-pool + exact top-L radix select + index-sorted compaction.
// One block (1024 threads) per head; each thread owns 8 contiguous positions.
__global__ __launch_bounds__(1024) void k_select(const float* __restrict__ prio,
                                                 int* __restrict__ keep,
                                                 float* __restrict__ hist_out,
                                                 float* __restrict__ pos_out) {
    __shared__ float pr[S];
    __shared__ int scan_buf[1024];
    __shared__ unsigned red[16];
    const int h = blockIdx.x;
    const int tid = threadIdx.x;
    const int lane = tid & 63, wid = tid >> 6;

    // Load this head's priority row into LDS (float4 vectorized)
    {
        const float4* src = (const float4*)(prio + (size_t)h * S);
        float4* dst4 = (float4*)pr;
        for (int i = tid; i < S / 4; i += 1024) dst4[i] = src[i];
    }
    __syncthreads();

    // Pooled keys (positive floats -> monotone uint bits)
    unsigned key[8];
    const int s0 = tid * 8;
#pragma unroll
    for (int j = 0; j < 8; ++j) {
        int s = s0 + j;
        float pooled;
        if (s >= S - OBS) {
            pooled = 1.0f;  // observation window always kept
        } else {
            int lo = s - 2; if (lo < 0) lo = 0;
            int hi = s + 3; if (hi > S) hi = S;
            float sum = 0.f;
            for (int i = lo; i < hi; ++i) sum += pr[i];
            pooled = sum / (float)(hi - lo);  // count_include_pad=False
        }
        key[j] = __float_as_uint(pooled);
    }

    // Binary radix select: find value of L-th largest key
    unsigned prefix = 0;
    int k = L;
    for (int b = 31; b >= 0; --b) {
        const unsigned bit = 1u << b;
        const unsigned want = prefix | bit;
        const unsigned mask = ~(bit - 1u);
        int cnt = 0;
#pragma unroll
        for (int j = 0; j < 8; ++j) cnt += ((key[j] & mask) == want) ? 1 : 0;
        unsigned c = (unsigned)cnt;
        for (int off = 32; off > 0; off >>= 1) c += __shfl_down(c, off);
        if (lane == 0) red[wid] = c;
        __syncthreads();
        unsigned total = 0;
#pragma unroll
        for (int w = 0; w < 16; ++w) total += red[w];
        __syncthreads();
        if ((int)total >= k) prefix = want; else k -= (int)total;
    }
    const unsigned T = prefix;
    const int needed_eq = k;  // take this many ==T elements, lowest index first

    // Scan 1: exclusive prefix of (#keys == T) across threads
    int local_eq = 0;
#pragma unroll
    for (int j = 0; j < 8; ++j) local_eq += (key[j] == T) ? 1 : 0;
    scan_buf[tid] = local_eq;
    __syncthreads();
    for (int off = 1; off < 1024; off <<= 1) {
        int v = scan_buf[tid];
        int add = (tid >= off) ? scan_buf[tid - off] : 0;
        __syncthreads();
        scan_buf[tid] = v + add;
        __syncthreads();
    }
    const int eq_before = scan_buf[tid] - local_eq;

    // Selection flags (index order => already sorted ascending)
    int sel_mask = 0, sel_count = 0;
    {
        int eqrank = eq_before;
#pragma unroll
        for (int j = 0; j < 8; ++j) {
            bool gt = key[j] > T;
            bool eq = key[j] == T;
            bool sl = gt || (eq && (eqrank < needed_eq));
            if (eq) eqrank++;
            if (sl) { sel_mask |= (1 << j); sel_count++; }
        }
    }
    __syncthreads();

    // Scan 2: exclusive prefix of selected counts -> output ranks
    scan_buf[tid] = sel_count;
    __syncthreads();
    for (int off = 1; off < 1024; off <<= 1) {
        int v = scan_buf[tid];
        int add = (tid >= off) ? scan_buf[tid - off] : 0;
        __syncthreads();
        scan_buf[tid] = v + add;
        __syncthreads();
    }
    int r = scan_buf[tid] - sel_count;

#pragma unroll
    for (int j = 0; j < 8; ++j) {
        if (sel_mask & (1 << j)) {
            int s = s0 + j;
            size_t o = (size_t)h * L + r;
            keep[o] = s;
            pos_out[o] = (float)s;     // harness reads flat buffer as f32
            hist_out[o] = pr[s];       // pre-pool priority gathered at keep idx
            r++;
        }
    }
}

// Kernel 3: gather selected K/V rows. 8 rows per 256-thread block; 32 lanes x float4 per row.
__global__ void k_gather(const float* __restrict__ kvK, const float* __restrict__ kvV,
                         const int* __restrict__ keep, float* __restrict__ out) {
    const int tid = threadIdx.x;
    const int row = blockIdx.x * 8 + (tid >> 5);   // 0 .. 2*H*L-1
    const int lane = tid & 31;
    const int tensor = row >> 16;                  // 0 = K, 1 = V
    const int idx = row & 65535;                   // h*L + r
    const int h = idx >> 11;
    const int s = keep[idx];
    const float* srcbase = tensor ? kvV : kvK;
    const float4* src = (const float4*)(srcbase + (size_t)(h * S + s) * D);
    float4* dst = (float4*)(out + (size_t)tensor * ((size_t)H * L * D) + (size_t)idx * D);
    dst[lane] = src[lane];
}

extern "C" void kernel_launch(void* const* d_in, const int* in_sizes, int n_in,
                              void* d_out, int out_size, void* d_ws, size_t ws_size,
                              hipStream_t stream) {
    const float* attn = (const float*)d_in[0];
    const float* k_val = (const float*)d_in[1];
    const float* v_val = (const float*)d_in[2];
    // d_in[3] = input_pos (unused by reference math)

    float* out = (float*)d_out;
    float* hist = out + (size_t)2 * H * L * D;   // offset 16777216
    float* pos = hist + (size_t)H * L;           // offset 16842752

    float* prio = (float*)d_ws;                                  // H*S floats = 1 MB
    int* keep = (int*)((char*)d_ws + (size_t)H * S * sizeof(float));  // H*L ints = 256 KB

    k_priority<<<256, 256, 0, stream>>>(attn, prio);
    k_select<<<H, 1024, 0, stream>>>(prio, keep, hist, pos);
    k_gather<<<(2 * H * L) / 8, 256, 0, stream>>>(k_val, v_val, keep, out);
}